// Round 5
// baseline (1186.908 us; speedup 1.0000x reference)
//
#include <hip/hip_runtime.h>
#include <hip/hip_bf16.h>

#define EPSV 1e-8f

typedef short bf16x8 __attribute__((ext_vector_type(8)));
typedef float f32x4  __attribute__((ext_vector_type(4)));

__device__ __forceinline__ float silu_f(float x) {
    // fast rcp (1 ulp) instead of precise divide (~8 VALU ops saved)
    return x * __builtin_amdgcn_rcpf(1.0f + __expf(-x));
}
__device__ __forceinline__ float bf2f(short v) {
    return __uint_as_float(((unsigned int)(unsigned short)v) << 16);
}
__device__ __forceinline__ short f2bfs(float f) {
    __hip_bfloat16 h = __float2bfloat16(f);
    return *(short*)&h;
}

// ======================= weight repack: f32 KxN(row-major, N=128) -> bf16 MFMA-B frags
#define MAXM 24
struct PackArgs {
    const float* src[MAXM];
    unsigned int doff[MAXM];
    int nchunk[MAXM];
    int nmat;
};

__global__ __launch_bounds__(256) void repack_kernel(PackArgs pa, __hip_bfloat16* base)
{
    int bid = blockIdx.x;
    int m = 0, c = bid;
    while (m < pa.nmat && c >= pa.nchunk[m]) { c -= pa.nchunk[m]; ++m; }
    const float* src = pa.src[m];
    __hip_bfloat16* dst = base + pa.doff[m] + (size_t)c * 4096;
    for (int o = threadIdx.x; o < 4096; o += 256) {
        int j = o & 7, n = (o >> 3) & 127, g = o >> 10;
        dst[o] = __float2bfloat16(src[(size_t)(c * 32 + g * 8 + j) * 128 + n]);
    }
}

// ======================= edge dst-sort: histogram -> scan -> scatter
__global__ __launch_bounds__(256) void hist_kernel(
    const int* __restrict__ ei, int* __restrict__ cnt, int E, int N)
{
    int e = blockIdx.x * 256 + threadIdx.x;
    int Etot = E + N;
    if (e < Etot) {
        int d = (e < E) ? ei[E + e] : (e - E);
        atomicAdd(&cnt[d], 1);
    }
}

__global__ __launch_bounds__(256) void scan_block_kernel(
    const int* __restrict__ cnt, int* __restrict__ off, int* __restrict__ part, int n)
{
    __shared__ int sdata[256];
    const int tid = threadIdx.x;
    const int base = blockIdx.x * 4096 + tid * 16;
    int loc[16]; int s = 0;
    #pragma unroll
    for (int i = 0; i < 16; ++i) {
        int idx = base + i;
        int v = (idx < n) ? cnt[idx] : 0;
        loc[i] = s; s += v;
    }
    sdata[tid] = s;
    __syncthreads();
    for (int st = 1; st < 256; st <<= 1) {
        int v = (tid >= st) ? sdata[tid - st] : 0;
        __syncthreads();
        sdata[tid] += v;
        __syncthreads();
    }
    int texc = (tid > 0) ? sdata[tid - 1] : 0;
    #pragma unroll
    for (int i = 0; i < 16; ++i) {
        int idx = base + i;
        if (idx < n) off[idx] = texc + loc[i];
    }
    if (tid == 255) part[blockIdx.x] = sdata[255];
}

__global__ void scan_part_kernel(int* part, int np)
{
    if (threadIdx.x == 0 && blockIdx.x == 0) {
        int run = 0;
        for (int i = 0; i < np; ++i) { int v = part[i]; part[i] = run; run += v; }
    }
}

__global__ __launch_bounds__(256) void scan_add_kernel(
    int* __restrict__ off, const int* __restrict__ part, int n)
{
    int idx = blockIdx.x * 4096 + threadIdx.x * 16;
    int p = part[blockIdx.x];
    #pragma unroll
    for (int i = 0; i < 16; ++i)
        if (idx + i < n) off[idx + i] += p;
}

__global__ __launch_bounds__(256) void scatter_kernel(
    const int* __restrict__ ei, int* __restrict__ off,
    int* __restrict__ esrc, int* __restrict__ edst, int E, int N)
{
    int e = blockIdx.x * 256 + threadIdx.x;
    int Etot = E + N;
    if (e < Etot) {
        int s, d;
        if (e < E) { s = ei[e]; d = ei[E + e]; }
        else       { s = d = e - E; }
        int p = atomicAdd(&off[d], 1);
        esrc[p] = s; edst[p] = d;
    }
}

// ======================= core MFMA tile GEMM (A in LDS, B packed global; 4 waves x 32 cols)
template<int LDA>
__device__ __forceinline__ void mfma_gemm(const __hip_bfloat16 (*At)[LDA], int acol0,
                                          const __hip_bfloat16* __restrict__ Bp,
                                          int kchunks, int w, int lane, f32x4 acc[4][2])
{
    const int ar = lane & 15, g = lane >> 4;
    const int bc = w * 32 + (lane & 15);
    for (int c = 0; c < kchunks; ++c) {
        const int ao = acol0 + c * 32 + g * 8;
        bf16x8 a0 = *(const bf16x8*)&At[ar +  0][ao];
        bf16x8 a1 = *(const bf16x8*)&At[ar + 16][ao];
        bf16x8 a2 = *(const bf16x8*)&At[ar + 32][ao];
        bf16x8 a3 = *(const bf16x8*)&At[ar + 48][ao];
        const __hip_bfloat16* bb = Bp + ((size_t)((c * 4 + g) * 128) + bc) * 8;
        bf16x8 b0 = *(const bf16x8*)(bb);
        bf16x8 b1 = *(const bf16x8*)(bb + 128);
        acc[0][0] = __builtin_amdgcn_mfma_f32_16x16x32_bf16(a0, b0, acc[0][0], 0, 0, 0);
        acc[1][0] = __builtin_amdgcn_mfma_f32_16x16x32_bf16(a1, b0, acc[1][0], 0, 0, 0);
        acc[2][0] = __builtin_amdgcn_mfma_f32_16x16x32_bf16(a2, b0, acc[2][0], 0, 0, 0);
        acc[3][0] = __builtin_amdgcn_mfma_f32_16x16x32_bf16(a3, b0, acc[3][0], 0, 0, 0);
        acc[0][1] = __builtin_amdgcn_mfma_f32_16x16x32_bf16(a0, b1, acc[0][1], 0, 0, 0);
        acc[1][1] = __builtin_amdgcn_mfma_f32_16x16x32_bf16(a1, b1, acc[1][1], 0, 0, 0);
        acc[2][1] = __builtin_amdgcn_mfma_f32_16x16x32_bf16(a2, b1, acc[2][1], 0, 0, 0);
        acc[3][1] = __builtin_amdgcn_mfma_f32_16x16x32_bf16(a3, b1, acc[3][1], 0, 0, 0);
    }
}

__device__ __forceinline__ void zacc(f32x4 acc[4][2]) {
    #pragma unroll
    for (int r = 0; r < 4; ++r)
        #pragma unroll
        for (int c = 0; c < 2; ++c) acc[r][c] = (f32x4){0.f, 0.f, 0.f, 0.f};
}

// ======================= embed (fp32): h = hin @ embW + b -> hbuf f32 + h16 bf16
__device__ __forceinline__ void gemm4x4(const float* __restrict__ Wg,
                                        const float* a0p, const float* a1p,
                                        const float* a2p, const float* a3p,
                                        int K, int o0, float acc[4][4]) {
    for (int k = 0; k < K; k += 4) {
        float4 a0 = *(const float4*)(a0p + k);
        float4 a1 = *(const float4*)(a1p + k);
        float4 a2 = *(const float4*)(a2p + k);
        float4 a3 = *(const float4*)(a3p + k);
        float4 w0 = *(const float4*)(Wg + (k + 0) * 128 + o0);
        float4 w1 = *(const float4*)(Wg + (k + 1) * 128 + o0);
        float4 w2 = *(const float4*)(Wg + (k + 2) * 128 + o0);
        float4 w3 = *(const float4*)(Wg + (k + 3) * 128 + o0);
        float av[4][4] = {{a0.x, a0.y, a0.z, a0.w}, {a1.x, a1.y, a1.z, a1.w},
                          {a2.x, a2.y, a2.z, a2.w}, {a3.x, a3.y, a3.z, a3.w}};
        float wv[4][4] = {{w0.x, w0.y, w0.z, w0.w}, {w1.x, w1.y, w1.z, w1.w},
                          {w2.x, w2.y, w2.z, w2.w}, {w3.x, w3.y, w3.z, w3.w}};
        #pragma unroll
        for (int i = 0; i < 4; ++i)
            #pragma unroll
            for (int kk = 0; kk < 4; ++kk)
                #pragma unroll
                for (int j = 0; j < 4; ++j)
                    acc[i][j] = fmaf(av[i][kk], wv[kk][j], acc[i][j]);
    }
}

__global__ __launch_bounds__(256) void embed_kernel(
    const float* __restrict__ hin, const float* __restrict__ W,
    const float* __restrict__ b, float* __restrict__ hbuf,
    __hip_bfloat16* __restrict__ h16, int N)
{
    __shared__ float in_tile[32][68];
    const int t = threadIdx.x;
    const int nb = blockIdx.x * 32;

    #pragma unroll
    for (int it = 0; it < 2; ++it) {
        int flat = t + 256 * it;
        int c = flat & 15, e = flat >> 4;
        int node = nb + e; if (node >= N) node = N - 1;
        *(float4*)(&in_tile[e][c * 4]) = *(const float4*)(hin + (size_t)node * 64 + c * 4);
    }
    __syncthreads();

    const int o0 = (t & 31) * 4;
    const int e0 = (t >> 5) * 4;
    float acc[4][4];
    #pragma unroll
    for (int i = 0; i < 4; ++i)
        #pragma unroll
        for (int j = 0; j < 4; ++j) acc[i][j] = 0.f;
    gemm4x4(W, &in_tile[e0][0], &in_tile[e0 + 1][0], &in_tile[e0 + 2][0], &in_tile[e0 + 3][0],
            64, o0, acc);
    float4 bv = *(const float4*)(b + o0);
    #pragma unroll
    for (int i = 0; i < 4; ++i) {
        int node = nb + e0 + i;
        if (node < N) {
            float v0 = acc[i][0] + bv.x, v1 = acc[i][1] + bv.y;
            float v2 = acc[i][2] + bv.z, v3 = acc[i][3] + bv.w;
            *(float4*)(&hbuf[(size_t)node * 128 + o0]) = make_float4(v0, v1, v2, v3);
            __hip_bfloat16* hp = h16 + (size_t)node * 128 + o0;
            hp[0] = __float2bfloat16(v0); hp[1] = __float2bfloat16(v1);
            hp[2] = __float2bfloat16(v2); hp[3] = __float2bfloat16(v3);
        }
    }
}

// ======================= standalone precompute (layer 0 only):
// U = h@W1a + b1, V = h@W1b, wnum = silu(h@cW1+cb1).cW2 + cb2
__global__ __launch_bounds__(256) void precompute_kernel(
    const __hip_bfloat16* __restrict__ h16,
    const __hip_bfloat16* __restrict__ W1p,
    const float* __restrict__ b1,
    const __hip_bfloat16* __restrict__ cW1p,
    const float* __restrict__ cb1, const float* __restrict__ cW2,
    const float* __restrict__ cb2,
    __hip_bfloat16* __restrict__ U16, __hip_bfloat16* __restrict__ V16,
    float* __restrict__ wnum, int N)
{
    __shared__ __hip_bfloat16 a8[64][136];
    __shared__ float redw[64][4];
    const int t = threadIdx.x;
    const int nb = blockIdx.x * 64;
    const int lane = t & 63, w = t >> 6, g = lane >> 4, l15 = lane & 15;

    #pragma unroll
    for (int it = 0; it < 4; ++it) {
        int flat = t + 256 * it;
        int c = flat & 15, e = flat >> 4;
        int node = nb + e; if (node >= N) node = N - 1;
        *(int4*)(&a8[e][c * 8]) = *(const int4*)(h16 + (size_t)node * 128 + c * 8);
    }
    __syncthreads();

    const int colA = w * 32 + l15, colB = colA + 16;
    f32x4 acc[4][2];

    // U (+b1)
    zacc(acc);
    mfma_gemm<136>(a8, 0, W1p, 4, w, lane, acc);
    {
        float bA = b1[colA], bB = b1[colB];
        #pragma unroll
        for (int r = 0; r < 4; ++r)
            #pragma unroll
            for (int q = 0; q < 4; ++q) {
                int node = nb + r * 16 + g * 4 + q;
                if (node < N) {
                    U16[(size_t)node * 128 + colA] = __float2bfloat16(acc[r][0][q] + bA);
                    U16[(size_t)node * 128 + colB] = __float2bfloat16(acc[r][1][q] + bB);
                }
            }
    }
    // V
    zacc(acc);
    mfma_gemm<136>(a8, 0, W1p + 4 * 4096, 4, w, lane, acc);
    #pragma unroll
    for (int r = 0; r < 4; ++r)
        #pragma unroll
        for (int q = 0; q < 4; ++q) {
            int node = nb + r * 16 + g * 4 + q;
            if (node < N) {
                V16[(size_t)node * 128 + colA] = __float2bfloat16(acc[r][0][q]);
                V16[(size_t)node * 128 + colB] = __float2bfloat16(acc[r][1][q]);
            }
        }
    // silu(h@cW1+cb1) . cW2
    zacc(acc);
    mfma_gemm<136>(a8, 0, cW1p, 4, w, lane, acc);
    {
        float cb1A = cb1[colA], cb1B = cb1[colB];
        float wA = cW2[colA], wB = cW2[colB];
        #pragma unroll
        for (int r = 0; r < 4; ++r)
            #pragma unroll
            for (int q = 0; q < 4; ++q) {
                float p = silu_f(acc[r][0][q] + cb1A) * wA
                        + silu_f(acc[r][1][q] + cb1B) * wB;
                p += __shfl_xor(p, 1);
                p += __shfl_xor(p, 2);
                p += __shfl_xor(p, 4);
                p += __shfl_xor(p, 8);
                if (l15 == 0) redw[r * 16 + g * 4 + q][w] = p;
            }
    }
    __syncthreads();
    if (t < 64 && nb + t < N)
        wnum[nb + t] = redw[t][0] + redw[t][1] + redw[t][2] + redw[t][3] + cb2[0];
}

// ======================= per-layer edge kernel: 128 edges / 512 threads,
// reg-prefetched gathers, single GEMM, sorted segmented reduce
__global__ __launch_bounds__(512, 4) void edge_kernel(
    const __hip_bfloat16* __restrict__ U16, const __hip_bfloat16* __restrict__ V16,
    const float* __restrict__ wnum, const float* __restrict__ posb,
    const int* __restrict__ esrc, const int* __restrict__ edst,
    const float* __restrict__ W1tail,
    const __hip_bfloat16* __restrict__ W2p, const float* __restrict__ b2,
    float* __restrict__ agg, float* __restrict__ pdel, int Etot)
{
    __shared__ __hip_bfloat16 m1s[128][136];   // reused for m2
    __shared__ int   dstl[128];
    __shared__ float relt[3][128], distl[128], wscl[128];

    const int t = threadIdx.x;                 // 0..511
    const int eb = blockIdx.x * 128;
    const int lane = t & 63, w = t >> 6;       // 8 waves
    const int g = lane >> 4, l15 = lane & 15;

    // --- prefetch: issue U/V gathers into registers (no LDS dependence)
    bf16x8 uvr[4], vvr[4];
    {
        const int c8 = t & 15;
        #pragma unroll
        for (int j = 0; j < 4; ++j) {
            int row = (t >> 4) + 32 * j;
            int e = eb + row;
            int s = 0, d = 0;
            if (e < Etot) { s = esrc[e]; d = edst[e]; }
            uvr[j] = *(const bf16x8*)(U16 + (size_t)d * 128 + c8 * 8);
            vvr[j] = *(const bf16x8*)(V16 + (size_t)s * 128 + c8 * 8);
        }
    }

    // --- per-row metadata (overlaps with gather latency)
    if (t < 128) {
        int e = eb + t;
        int s = 0, d = -1;
        if (e < Etot) { s = esrc[e]; d = edst[e]; }
        dstl[t] = d;
        int dd = (d < 0) ? 0 : d;
        float rx = posb[3 * s + 0] - posb[3 * dd + 0];
        float ry = posb[3 * s + 1] - posb[3 * dd + 1];
        float rz = posb[3 * s + 2] - posb[3 * dd + 2];
        float dist = sqrtf(rx * rx + ry * ry + rz * rz);
        relt[0][t] = rx; relt[1][t] = ry; relt[2][t] = rz;
        distl[t] = dist;
        wscl[t] = wnum[s] * __builtin_amdgcn_rcpf(dist + EPSV);
    }
    __syncthreads();

    // --- m1 = silu(U[d](+b1) + V[s] + dist*wt)
    {
        const int c8 = t & 15;
        float wt[8];
        *(float4*)&wt[0] = *(const float4*)(W1tail + c8 * 8);
        *(float4*)&wt[4] = *(const float4*)(W1tail + c8 * 8 + 4);
        #pragma unroll
        for (int j = 0; j < 4; ++j) {
            int row = (t >> 4) + 32 * j;
            float dv = distl[row];
            bf16x8 res;
            #pragma unroll
            for (int k = 0; k < 8; ++k) {
                float x = bf2f(uvr[j][k]) + bf2f(vvr[j][k]) + dv * wt[k];
                res[k] = f2bfs(silu_f(x));
            }
            *(bf16x8*)(&m1s[row][c8 * 8]) = res;
        }
    }
    __syncthreads();

    // --- GEMM2: wave w owns cols w*16..w*16+15, all 128 rows
    const int col = w * 16 + l15;
    f32x4 acc8[8];
    #pragma unroll
    for (int rt = 0; rt < 8; ++rt) acc8[rt] = (f32x4){0.f, 0.f, 0.f, 0.f};
    for (int c = 0; c < 4; ++c) {
        const int ao = c * 32 + g * 8;
        bf16x8 b0 = *(const bf16x8*)(W2p + ((size_t)((c * 4 + g) * 128) + col) * 8);
        #pragma unroll
        for (int rt = 0; rt < 8; ++rt) {
            bf16x8 a = *(const bf16x8*)&m1s[l15 + 16 * rt][ao];
            acc8[rt] = __builtin_amdgcn_mfma_f32_16x16x32_bf16(a, b0, acc8[rt], 0, 0, 0);
        }
    }
    __syncthreads();   // all m1s reads done

    // --- m2 = silu(. + b2) back into LDS (bf16)
    {
        float b2c = b2[col];
        #pragma unroll
        for (int rt = 0; rt < 8; ++rt)
            #pragma unroll
            for (int q = 0; q < 4; ++q) {
                int row = rt * 16 + g * 4 + q;
                m1s[row][col] = __float2bfloat16(silu_f(acc8[rt][q] + b2c));
            }
    }
    __syncthreads();

    // --- segmented reduction by dst (rows sorted): 4 threads/col x 32 rows
    {
        int rcol = t & 127, qtr = t >> 7;
        int r0 = qtr * 32;
        float a = 0.f;
        int cur = dstl[r0];
        #pragma unroll 4
        for (int r = r0; r < r0 + 32; ++r) {
            int d = dstl[r];
            if (d != cur) {
                if (cur >= 0) atomicAdd(&agg[(size_t)cur * 128 + rcol], a);
                a = 0.f; cur = d;
            }
            if (d >= 0) a += bf2f(*(const short*)&m1s[r][rcol]);
        }
        if (cur >= 0) atomicAdd(&agg[(size_t)cur * 128 + rcol], a);
    }

    // --- pdel scatter
    if (t < 384) {
        int e = t / 3, comp = t % 3;
        if (dstl[e] >= 0)
            atomicAdd(&pdel[(size_t)dstl[e] * 3 + comp], wscl[e] * relt[comp][e]);
    }
}

// ======================= per-layer node kernel (+ fused precompute for next layer)
__global__ __launch_bounds__(256) void node_mfma_kernel(
    float* __restrict__ hbuf, __hip_bfloat16* __restrict__ h16,
    const float* __restrict__ agg,
    float* __restrict__ posb, const float* __restrict__ pdel,
    const __hip_bfloat16* __restrict__ W1p, const float* __restrict__ b1,
    const __hip_bfloat16* __restrict__ W2p, const float* __restrict__ b2,
    const __hip_bfloat16* __restrict__ nxtW1p, const float* __restrict__ nxt_b1,
    const __hip_bfloat16* __restrict__ nxt_cW1p, const float* __restrict__ nxt_cb1,
    const float* __restrict__ nxt_cW2, const float* __restrict__ nxt_cb2,
    __hip_bfloat16* __restrict__ U16, __hip_bfloat16* __restrict__ V16,
    float* __restrict__ wnum,
    int N, int doPre)
{
    __shared__ __hip_bfloat16 a_t[64][264];   // [h | agg] then [newh | agg]
    __shared__ __hip_bfloat16 us[64][136];
    __shared__ float redw[64][4];
    const int t = threadIdx.x;
    const int nb = blockIdx.x * 64;
    const int lane = t & 63, w = t >> 6, g = lane >> 4, l15 = lane & 15;

    #pragma unroll
    for (int it = 0; it < 4; ++it) {
        int flat = t + 256 * it;
        int c = flat & 15, e = flat >> 4;
        int node = nb + e; if (node >= N) node = N - 1;
        *(int4*)(&a_t[e][c * 8]) = *(const int4*)(h16 + (size_t)node * 128 + c * 8);
    }
    #pragma unroll
    for (int it = 0; it < 8; ++it) {
        int flat = t + 256 * it;
        int c = flat & 31, e = flat >> 5;
        int node = nb + e; if (node >= N) node = N - 1;
        float4 v = *(const float4*)(agg + (size_t)node * 128 + c * 4);
        __hip_bfloat16* p = &a_t[e][128 + c * 4];
        p[0] = __float2bfloat16(v.x); p[1] = __float2bfloat16(v.y);
        p[2] = __float2bfloat16(v.z); p[3] = __float2bfloat16(v.w);
    }
    __syncthreads();

    const int colA = w * 32 + l15, colB = colA + 16;
    f32x4 acc[4][2];

    zacc(acc);
    mfma_gemm<264>(a_t, 0, W1p, 8, w, lane, acc);
    {
        float b1a = b1[colA], b1b = b1[colB];
        #pragma unroll
        for (int r = 0; r < 4; ++r)
            #pragma unroll
            for (int q = 0; q < 4; ++q) {
                int row = r * 16 + g * 4 + q;
                us[row][colA] = __float2bfloat16(silu_f(acc[r][0][q] + b1a));
                us[row][colB] = __float2bfloat16(silu_f(acc[r][1][q] + b1b));
            }
    }
    __syncthreads();

    zacc(acc);
    mfma_gemm<136>(us, 0, W2p, 4, w, lane, acc);
    {
        float b2a = b2[colA], b2b = b2[colB];
        #pragma unroll
        for (int r = 0; r < 4; ++r)
            #pragma unroll
            for (int q = 0; q < 4; ++q) {
                int row = r * 16 + g * 4 + q;
                int node = nb + row;
                if (node < N) {
                    size_t off = (size_t)node * 128;
                    float va = hbuf[off + colA] + acc[r][0][q] + b2a;
                    float vb = hbuf[off + colB] + acc[r][1][q] + b2b;
                    hbuf[off + colA] = va; hbuf[off + colB] = vb;
                    __hip_bfloat16 ha = __float2bfloat16(va), hb = __float2bfloat16(vb);
                    h16[off + colA] = ha; h16[off + colB] = hb;
                    a_t[row][colA] = ha; a_t[row][colB] = hb;   // stage new h for precompute
                } else {
                    a_t[row][colA] = __float2bfloat16(0.f);
                    a_t[row][colB] = __float2bfloat16(0.f);
                }
            }
    }
    if (t < 192) {
        int e = t / 3, comp = t % 3;
        int node = nb + e;
        if (node < N) posb[3 * node + comp] += pdel[3 * node + comp];
    }

    if (!doPre) return;
    __syncthreads();   // new h staged in a_t[.][0..127]

    // U_next = newh @ W1a_next + b1_next
    zacc(acc);
    mfma_gemm<264>(a_t, 0, nxtW1p, 4, w, lane, acc);
    {
        float bA = nxt_b1[colA], bB = nxt_b1[colB];
        #pragma unroll
        for (int r = 0; r < 4; ++r)
            #pragma unroll
            for (int q = 0; q < 4; ++q) {
                int node = nb + r * 16 + g * 4 + q;
                if (node < N) {
                    U16[(size_t)node * 128 + colA] = __float2bfloat16(acc[r][0][q] + bA);
                    U16[(size_t)node * 128 + colB] = __float2bfloat16(acc[r][1][q] + bB);
                }
            }
    }
    // V_next = newh @ W1b_next
    zacc(acc);
    mfma_gemm<264>(a_t, 0, nxtW1p + 4 * 4096, 4, w, lane, acc);
    #pragma unroll
    for (int r = 0; r < 4; ++r)
        #pragma unroll
        for (int q = 0; q < 4; ++q) {
            int node = nb + r * 16 + g * 4 + q;
            if (node < N) {
                V16[(size_t)node * 128 + colA] = __float2bfloat16(acc[r][0][q]);
                V16[(size_t)node * 128 + colB] = __float2bfloat16(acc[r][1][q]);
            }
        }
    // wnum_next = silu(newh @ cW1_next + cb1_next) . cW2_next + cb2_next
    zacc(acc);
    mfma_gemm<264>(a_t, 0, nxt_cW1p, 4, w, lane, acc);
    {
        float cb1A = nxt_cb1[colA], cb1B = nxt_cb1[colB];
        float wA = nxt_cW2[colA], wB = nxt_cW2[colB];
        #pragma unroll
        for (int r = 0; r < 4; ++r)
            #pragma unroll
            for (int q = 0; q < 4; ++q) {
                float p = silu_f(acc[r][0][q] + cb1A) * wA
                        + silu_f(acc[r][1][q] + cb1B) * wB;
                p += __shfl_xor(p, 1);
                p += __shfl_xor(p, 2);
                p += __shfl_xor(p, 4);
                p += __shfl_xor(p, 8);
                if (l15 == 0) redw[r * 16 + g * 4 + q][w] = p;
            }
    }
    __syncthreads();
    if (t < 64 && nb + t < N)
        wnum[nb + t] = redw[t][0] + redw[t][1] + redw[t][2] + redw[t][3] + nxt_cb2[0];
}

// ======================= output head (MFMA)
__global__ __launch_bounds__(256) void out_mfma_kernel(
    const __hip_bfloat16* __restrict__ h16,
    const __hip_bfloat16* __restrict__ W1p, const float* __restrict__ b1,
    const __hip_bfloat16* __restrict__ W2p, const float* __restrict__ b2,
    float* __restrict__ outp, int N)
{
    __shared__ __hip_bfloat16 a8[64][136];
    __shared__ __hip_bfloat16 us[64][136];
    const int t = threadIdx.x;
    const int nb = blockIdx.x * 64;
    const int lane = t & 63, w = t >> 6, g = lane >> 4;

    #pragma unroll
    for (int it = 0; it < 4; ++it) {
        int flat = t + 256 * it;
        int c = flat & 15, e = flat >> 4;
        int node = nb + e; if (node >= N) node = N - 1;
        *(int4*)(&a8[e][c * 8]) = *(const int4*)(h16 + (size_t)node * 128 + c * 8);
    }
    __syncthreads();

    const int colA = w * 32 + (lane & 15), colB = colA + 16;
    f32x4 acc[4][2];

    zacc(acc);
    mfma_gemm<136>(a8, 0, W1p, 4, w, lane, acc);
    {
        float b1a = b1[colA], b1b = b1[colB];
        #pragma unroll
        for (int r = 0; r < 4; ++r)
            #pragma unroll
            for (int q = 0; q < 4; ++q) {
                int row = r * 16 + g * 4 + q;
                us[row][colA] = __float2bfloat16(silu_f(acc[r][0][q] + b1a));
                us[row][colB] = __float2bfloat16(silu_f(acc[r][1][q] + b1b));
            }
    }
    __syncthreads();

    zacc(acc);
    mfma_gemm<136>(us, 0, W2p, 4, w, lane, acc);
    {
        float b2a = b2[colA], b2b = b2[colB];
        #pragma unroll
        for (int r = 0; r < 4; ++r)
            #pragma unroll
            for (int q = 0; q < 4; ++q) {
                int row = r * 16 + g * 4 + q;
                int node = nb + row;
                if (node < N) {
                    outp[(size_t)node * 128 + colA] = acc[r][0][q] + b2a;
                    outp[(size_t)node * 128 + colB] = acc[r][1][q] + b2b;
                }
            }
    }
}

// =======================
extern "C" void kernel_launch(void* const* d_in, const int* in_sizes, int n_in,
                              void* d_out, int out_size, void* d_ws, size_t ws_size,
                              hipStream_t stream)
{
    const float* hin  = (const float*)d_in[0];
    const float* pos  = (const float*)d_in[1];
    const int*   ei   = (const int*)d_in[2];
    const float* embW = (const float*)d_in[3];
    const float* embb = (const float*)d_in[4];
    const float* mW1  = (const float*)d_in[5];
    const float* mb1  = (const float*)d_in[6];
    const float* mW2  = (const float*)d_in[7];
    const float* mb2  = (const float*)d_in[8];
    const float* cW1  = (const float*)d_in[9];
    const float* cb1  = (const float*)d_in[10];
    const float* cW2  = (const float*)d_in[11];
    const float* cb2  = (const float*)d_in[12];
    const float* nW1  = (const float*)d_in[13];
    const float* nb1  = (const float*)d_in[14];
    const float* nW2  = (const float*)d_in[15];
    const float* nb2  = (const float*)d_in[16];
    const float* oW1  = (const float*)d_in[17];
    const float* ob1  = (const float*)d_in[18];
    const float* oW2  = (const float*)d_in[19];
    const float* ob2  = (const float*)d_in[20];

    const int N = in_sizes[0] / 64;
    const int E = in_sizes[2] / 2;
    const int Etot = E + N;

    float* hbuf = (float*)d_ws;                                  // N*128 f32
    float* aggb = hbuf + (size_t)N * 128;                        // N*128 f32
    float* posb = aggb + (size_t)N * 128;                        // N*3
    float* pdel = posb + (size_t)N * 3;                          // N*3
    float* wnum = pdel + (size_t)N * 3;                          // N f32
    __hip_bfloat16* h16 = (__hip_bfloat16*)(wnum + N);           // N*128 bf16
    __hip_bfloat16* U16 = h16 + (size_t)N * 128;                 // N*128 bf16
    __hip_bfloat16* V16 = U16 + (size_t)N * 128;                 // N*128 bf16
    __hip_bfloat16* packed = V16 + (size_t)N * 128;              // 120*4096 bf16
    int* cnt  = (int*)(packed + 120 * 4096);                     // N
    int* soff = cnt + N;                                         // N
    int* part = soff + N;                                        // 64
    int* esrc = part + 64;                                       // Etot
    int* edst = esrc + Etot;                                     // Etot
    float* outp = (float*)d_out;

    // ---- weight repack descriptors
    PackArgs pa;
    int nm = 0; unsigned int poff = 0; int totalChunks = 0;
    auto addm = [&](const float* s, int kc) {
        pa.src[nm] = s; pa.doff[nm] = poff; pa.nchunk[nm] = kc;
        poff += (unsigned int)kc * 4096; totalChunks += kc; ++nm;
    };
    for (int l = 0; l < 4; ++l) {
        addm(mW1 + (size_t)l * 257 * 128, 8);
        addm(mW2 + (size_t)l * 128 * 128, 4);
        addm(cW1 + (size_t)l * 128 * 128, 4);
        addm(nW1 + (size_t)l * 256 * 128, 8);
        addm(nW2 + (size_t)l * 128 * 128, 4);
    }
    addm(oW1, 4);
    addm(oW2, 4);
    pa.nmat = nm;

    const unsigned int LSTRIDE = 28 * 4096;

    hipMemcpyAsync(posb, pos, (size_t)N * 3 * sizeof(float),
                   hipMemcpyDeviceToDevice, stream);
    repack_kernel<<<totalChunks, 256, 0, stream>>>(pa, packed);

    // ---- dst-sort edges (once)
    const int scanBlocks = (N + 4095) / 4096;
    hipMemsetAsync(cnt, 0, (size_t)N * sizeof(int), stream);
    hist_kernel<<<(Etot + 255) / 256, 256, 0, stream>>>(ei, cnt, E, N);
    scan_block_kernel<<<scanBlocks, 256, 0, stream>>>(cnt, soff, part, N);
    scan_part_kernel<<<1, 64, 0, stream>>>(part, scanBlocks);
    scan_add_kernel<<<scanBlocks, 256, 0, stream>>>(soff, part, N);
    scatter_kernel<<<(Etot + 255) / 256, 256, 0, stream>>>(ei, soff, esrc, edst, E, N);

    const int nodeBlocks32 = (N + 31) / 32;
    const int nodeBlocks64 = (N + 63) / 64;
    const int edgeBlocks   = (Etot + 127) / 128;

    embed_kernel<<<nodeBlocks32, 256, 0, stream>>>(hin, embW, embb, hbuf, h16, N);

    // precompute for layer 0 (b1 folded into U)
    precompute_kernel<<<nodeBlocks64, 256, 0, stream>>>(
        h16, packed, mb1, packed + 12 * 4096,
        cb1, cW2, cb2, U16, V16, wnum, N);

    for (int l = 0; l < 4; ++l) {
        hipMemsetAsync(aggb, 0, (size_t)N * 128 * sizeof(float), stream);
        hipMemsetAsync(pdel, 0, (size_t)N * 3 * sizeof(float), stream);
        const __hip_bfloat16* lp = packed + (size_t)l * LSTRIDE;
        edge_kernel<<<edgeBlocks, 512, 0, stream>>>(
            U16, V16, wnum, posb, esrc, edst,
            mW1 + (size_t)l * 257 * 128 + 256 * 128,
            lp + 8 * 4096, mb2 + l * 128,
            aggb, pdel, Etot);
        const int ln = (l < 3) ? (l + 1) : l;   // valid pointers even when doPre=0
        const __hip_bfloat16* lpn = packed + (size_t)ln * LSTRIDE;
        node_mfma_kernel<<<nodeBlocks64, 256, 0, stream>>>(
            hbuf, h16, aggb, posb, pdel,
            lp + 16 * 4096, nb1 + l * 128,
            lp + 24 * 4096, nb2 + l * 128,
            lpn, mb1 + (size_t)ln * 128,
            lpn + 12 * 4096, cb1 + (size_t)ln * 128,
            cW2 + (size_t)ln * 128, cb2 + ln,
            U16, V16, wnum,
            N, (l < 3) ? 1 : 0);
    }
    out_mfma_kernel<<<nodeBlocks64, 256, 0, stream>>>(
        h16, packed + (size_t)4 * LSTRIDE, ob1,
        packed + (size_t)4 * LSTRIDE + 4 * 4096, ob2, outp, N);

    hipMemcpyAsync(outp + (size_t)N * 128, posb, (size_t)N * 3 * sizeof(float),
                   hipMemcpyDeviceToDevice, stream);
}

// Round 7
// 1032.021 us; speedup vs baseline: 1.1501x; 1.1501x over previous
//
#include <hip/hip_runtime.h>
#include <hip/hip_bf16.h>

#define EPSV 1e-8f

typedef short bf16x8 __attribute__((ext_vector_type(8)));
typedef float f32x4  __attribute__((ext_vector_type(4)));

__device__ __forceinline__ float silu_f(float x) {
    return x * __builtin_amdgcn_rcpf(1.0f + __expf(-x));
}
__device__ __forceinline__ float bf2f(short v) {
    return __uint_as_float(((unsigned int)(unsigned short)v) << 16);
}
__device__ __forceinline__ short f2bfs(float f) {
    __hip_bfloat16 h = __float2bfloat16(f);
    return *(short*)&h;
}

// ======================= weight repack: f32 KxN(row-major, N=128) -> bf16 MFMA-B frags
#define MAXM 24
struct PackArgs {
    const float* src[MAXM];
    unsigned int doff[MAXM];
    int nchunk[MAXM];
    int nmat;
};

__global__ __launch_bounds__(256) void repack_kernel(PackArgs pa, __hip_bfloat16* base)
{
    int bid = blockIdx.x;
    int m = 0, c = bid;
    while (m < pa.nmat && c >= pa.nchunk[m]) { c -= pa.nchunk[m]; ++m; }
    const float* src = pa.src[m];
    __hip_bfloat16* dst = base + pa.doff[m] + (size_t)c * 4096;
    for (int o = threadIdx.x; o < 4096; o += 256) {
        int j = o & 7, n = (o >> 3) & 127, g = o >> 10;
        dst[o] = __float2bfloat16(src[(size_t)(c * 32 + g * 8 + j) * 128 + n]);
    }
}

// ======================= edge dst-sort: histogram -> scan -> scatter
__global__ __launch_bounds__(256) void hist_kernel(
    const int* __restrict__ ei, int* __restrict__ cnt, int E, int N)
{
    int e = blockIdx.x * 256 + threadIdx.x;
    int Etot = E + N;
    if (e < Etot) {
        int d = (e < E) ? ei[E + e] : (e - E);
        atomicAdd(&cnt[d], 1);
    }
}

__global__ __launch_bounds__(256) void scan_block_kernel(
    const int* __restrict__ cnt, int* __restrict__ off, int* __restrict__ part, int n)
{
    __shared__ int sdata[256];
    const int tid = threadIdx.x;
    const int base = blockIdx.x * 4096 + tid * 16;
    int loc[16]; int s = 0;
    #pragma unroll
    for (int i = 0; i < 16; ++i) {
        int idx = base + i;
        int v = (idx < n) ? cnt[idx] : 0;
        loc[i] = s; s += v;
    }
    sdata[tid] = s;
    __syncthreads();
    for (int st = 1; st < 256; st <<= 1) {
        int v = (tid >= st) ? sdata[tid - st] : 0;
        __syncthreads();
        sdata[tid] += v;
        __syncthreads();
    }
    int texc = (tid > 0) ? sdata[tid - 1] : 0;
    #pragma unroll
    for (int i = 0; i < 16; ++i) {
        int idx = base + i;
        if (idx < n) off[idx] = texc + loc[i];
    }
    if (tid == 255) part[blockIdx.x] = sdata[255];
}

__global__ void scan_part_kernel(int* part, int np)
{
    if (threadIdx.x == 0 && blockIdx.x == 0) {
        int run = 0;
        for (int i = 0; i < np; ++i) { int v = part[i]; part[i] = run; run += v; }
    }
}

__global__ __launch_bounds__(256) void scan_add_kernel(
    int* __restrict__ off, const int* __restrict__ part, int n)
{
    int idx = blockIdx.x * 4096 + threadIdx.x * 16;
    int p = part[blockIdx.x];
    #pragma unroll
    for (int i = 0; i < 16; ++i)
        if (idx + i < n) off[idx + i] += p;
}

__global__ __launch_bounds__(256) void scatter_kernel(
    const int* __restrict__ ei, int* __restrict__ off,
    int* __restrict__ esrc, int* __restrict__ edst, int E, int N)
{
    int e = blockIdx.x * 256 + threadIdx.x;
    int Etot = E + N;
    if (e < Etot) {
        int s, d;
        if (e < E) { s = ei[e]; d = ei[E + e]; }
        else       { s = d = e - E; }
        int p = atomicAdd(&off[d], 1);
        esrc[p] = s; edst[p] = d;
    }
}

// ======================= core MFMA tile GEMM (A in LDS, B packed global; 4 waves x 32 cols)
template<int LDA>
__device__ __forceinline__ void mfma_gemm(const __hip_bfloat16 (*At)[LDA], int acol0,
                                          const __hip_bfloat16* __restrict__ Bp,
                                          int kchunks, int w, int lane, f32x4 acc[4][2])
{
    const int ar = lane & 15, g = lane >> 4;
    const int bc = w * 32 + (lane & 15);
    for (int c = 0; c < kchunks; ++c) {
        const int ao = acol0 + c * 32 + g * 8;
        bf16x8 a0 = *(const bf16x8*)&At[ar +  0][ao];
        bf16x8 a1 = *(const bf16x8*)&At[ar + 16][ao];
        bf16x8 a2 = *(const bf16x8*)&At[ar + 32][ao];
        bf16x8 a3 = *(const bf16x8*)&At[ar + 48][ao];
        const __hip_bfloat16* bb = Bp + ((size_t)((c * 4 + g) * 128) + bc) * 8;
        bf16x8 b0 = *(const bf16x8*)(bb);
        bf16x8 b1 = *(const bf16x8*)(bb + 128);
        acc[0][0] = __builtin_amdgcn_mfma_f32_16x16x32_bf16(a0, b0, acc[0][0], 0, 0, 0);
        acc[1][0] = __builtin_amdgcn_mfma_f32_16x16x32_bf16(a1, b0, acc[1][0], 0, 0, 0);
        acc[2][0] = __builtin_amdgcn_mfma_f32_16x16x32_bf16(a2, b0, acc[2][0], 0, 0, 0);
        acc[3][0] = __builtin_amdgcn_mfma_f32_16x16x32_bf16(a3, b0, acc[3][0], 0, 0, 0);
        acc[0][1] = __builtin_amdgcn_mfma_f32_16x16x32_bf16(a0, b1, acc[0][1], 0, 0, 0);
        acc[1][1] = __builtin_amdgcn_mfma_f32_16x16x32_bf16(a1, b1, acc[1][1], 0, 0, 0);
        acc[2][1] = __builtin_amdgcn_mfma_f32_16x16x32_bf16(a2, b1, acc[2][1], 0, 0, 0);
        acc[3][1] = __builtin_amdgcn_mfma_f32_16x16x32_bf16(a3, b1, acc[3][1], 0, 0, 0);
    }
}

__device__ __forceinline__ void zacc(f32x4 acc[4][2]) {
    #pragma unroll
    for (int r = 0; r < 4; ++r)
        #pragma unroll
        for (int c = 0; c < 2; ++c) acc[r][c] = (f32x4){0.f, 0.f, 0.f, 0.f};
}

// ======================= embed (fp32): h = hin @ embW + b -> hbuf f32 + h16 bf16
__device__ __forceinline__ void gemm4x4(const float* __restrict__ Wg,
                                        const float* a0p, const float* a1p,
                                        const float* a2p, const float* a3p,
                                        int K, int o0, float acc[4][4]) {
    for (int k = 0; k < K; k += 4) {
        float4 a0 = *(const float4*)(a0p + k);
        float4 a1 = *(const float4*)(a1p + k);
        float4 a2 = *(const float4*)(a2p + k);
        float4 a3 = *(const float4*)(a3p + k);
        float4 w0 = *(const float4*)(Wg + (k + 0) * 128 + o0);
        float4 w1 = *(const float4*)(Wg + (k + 1) * 128 + o0);
        float4 w2 = *(const float4*)(Wg + (k + 2) * 128 + o0);
        float4 w3 = *(const float4*)(Wg + (k + 3) * 128 + o0);
        float av[4][4] = {{a0.x, a0.y, a0.z, a0.w}, {a1.x, a1.y, a1.z, a1.w},
                          {a2.x, a2.y, a2.z, a2.w}, {a3.x, a3.y, a3.z, a3.w}};
        float wv[4][4] = {{w0.x, w0.y, w0.z, w0.w}, {w1.x, w1.y, w1.z, w1.w},
                          {w2.x, w2.y, w2.z, w2.w}, {w3.x, w3.y, w3.z, w3.w}};
        #pragma unroll
        for (int i = 0; i < 4; ++i)
            #pragma unroll
            for (int kk = 0; kk < 4; ++kk)
                #pragma unroll
                for (int j = 0; j < 4; ++j)
                    acc[i][j] = fmaf(av[i][kk], wv[kk][j], acc[i][j]);
    }
}

__global__ __launch_bounds__(256) void embed_kernel(
    const float* __restrict__ hin, const float* __restrict__ W,
    const float* __restrict__ b, float* __restrict__ hbuf,
    __hip_bfloat16* __restrict__ h16, int N)
{
    __shared__ float in_tile[32][68];
    const int t = threadIdx.x;
    const int nb = blockIdx.x * 32;

    #pragma unroll
    for (int it = 0; it < 2; ++it) {
        int flat = t + 256 * it;
        int c = flat & 15, e = flat >> 4;
        int node = nb + e; if (node >= N) node = N - 1;
        *(float4*)(&in_tile[e][c * 4]) = *(const float4*)(hin + (size_t)node * 64 + c * 4);
    }
    __syncthreads();

    const int o0 = (t & 31) * 4;
    const int e0 = (t >> 5) * 4;
    float acc[4][4];
    #pragma unroll
    for (int i = 0; i < 4; ++i)
        #pragma unroll
        for (int j = 0; j < 4; ++j) acc[i][j] = 0.f;
    gemm4x4(W, &in_tile[e0][0], &in_tile[e0 + 1][0], &in_tile[e0 + 2][0], &in_tile[e0 + 3][0],
            64, o0, acc);
    float4 bv = *(const float4*)(b + o0);
    #pragma unroll
    for (int i = 0; i < 4; ++i) {
        int node = nb + e0 + i;
        if (node < N) {
            float v0 = acc[i][0] + bv.x, v1 = acc[i][1] + bv.y;
            float v2 = acc[i][2] + bv.z, v3 = acc[i][3] + bv.w;
            *(float4*)(&hbuf[(size_t)node * 128 + o0]) = make_float4(v0, v1, v2, v3);
            __hip_bfloat16* hp = h16 + (size_t)node * 128 + o0;
            hp[0] = __float2bfloat16(v0); hp[1] = __float2bfloat16(v1);
            hp[2] = __float2bfloat16(v2); hp[3] = __float2bfloat16(v3);
        }
    }
}

// ======================= standalone precompute (layer 0 only)
__global__ __launch_bounds__(256) void precompute_kernel(
    const __hip_bfloat16* __restrict__ h16,
    const __hip_bfloat16* __restrict__ W1p,
    const float* __restrict__ b1,
    const __hip_bfloat16* __restrict__ cW1p,
    const float* __restrict__ cb1, const float* __restrict__ cW2,
    const float* __restrict__ cb2,
    __hip_bfloat16* __restrict__ U16, __hip_bfloat16* __restrict__ V16,
    float* __restrict__ wnum, int N)
{
    __shared__ __hip_bfloat16 a8[64][136];
    __shared__ float redw[64][4];
    const int t = threadIdx.x;
    const int nb = blockIdx.x * 64;
    const int lane = t & 63, w = t >> 6, g = lane >> 4, l15 = lane & 15;

    #pragma unroll
    for (int it = 0; it < 4; ++it) {
        int flat = t + 256 * it;
        int c = flat & 15, e = flat >> 4;
        int node = nb + e; if (node >= N) node = N - 1;
        *(int4*)(&a8[e][c * 8]) = *(const int4*)(h16 + (size_t)node * 128 + c * 8);
    }
    __syncthreads();

    const int colA = w * 32 + l15, colB = colA + 16;
    f32x4 acc[4][2];

    zacc(acc);
    mfma_gemm<136>(a8, 0, W1p, 4, w, lane, acc);
    {
        float bA = b1[colA], bB = b1[colB];
        #pragma unroll
        for (int r = 0; r < 4; ++r)
            #pragma unroll
            for (int q = 0; q < 4; ++q) {
                int node = nb + r * 16 + g * 4 + q;
                if (node < N) {
                    U16[(size_t)node * 128 + colA] = __float2bfloat16(acc[r][0][q] + bA);
                    U16[(size_t)node * 128 + colB] = __float2bfloat16(acc[r][1][q] + bB);
                }
            }
    }
    zacc(acc);
    mfma_gemm<136>(a8, 0, W1p + 4 * 4096, 4, w, lane, acc);
    #pragma unroll
    for (int r = 0; r < 4; ++r)
        #pragma unroll
        for (int q = 0; q < 4; ++q) {
            int node = nb + r * 16 + g * 4 + q;
            if (node < N) {
                V16[(size_t)node * 128 + colA] = __float2bfloat16(acc[r][0][q]);
                V16[(size_t)node * 128 + colB] = __float2bfloat16(acc[r][1][q]);
            }
        }
    zacc(acc);
    mfma_gemm<136>(a8, 0, cW1p, 4, w, lane, acc);
    {
        float cb1A = cb1[colA], cb1B = cb1[colB];
        float wA = cW2[colA], wB = cW2[colB];
        #pragma unroll
        for (int r = 0; r < 4; ++r)
            #pragma unroll
            for (int q = 0; q < 4; ++q) {
                float p = silu_f(acc[r][0][q] + cb1A) * wA
                        + silu_f(acc[r][1][q] + cb1B) * wB;
                p += __shfl_xor(p, 1);
                p += __shfl_xor(p, 2);
                p += __shfl_xor(p, 4);
                p += __shfl_xor(p, 8);
                if (l15 == 0) redw[r * 16 + g * 4 + q][w] = p;
            }
    }
    __syncthreads();
    if (t < 64 && nb + t < N)
        wnum[nb + t] = redw[t][0] + redw[t][1] + redw[t][2] + redw[t][3] + cb2[0];
}

// ======================= per-layer edge kernel (round-4 proven structure:
// 64 edges / 256 threads, serial segmented reduce; fast silu, b1 folded into U)
__global__ __launch_bounds__(256) void edge_kernel(
    const __hip_bfloat16* __restrict__ U16, const __hip_bfloat16* __restrict__ V16,
    const float* __restrict__ wnum, const float* __restrict__ posb,
    const int* __restrict__ esrc, const int* __restrict__ edst,
    const float* __restrict__ W1tail,
    const __hip_bfloat16* __restrict__ W2p, const float* __restrict__ b2,
    float* __restrict__ agg, float* __restrict__ pdel, int Etot)
{
    __shared__ __hip_bfloat16 m1s[64][136];    // reused for m2 after GEMM2
    __shared__ int   srcl[64], dstl[64];
    __shared__ float relt[3][64], distl[64], wscl[64];

    const int t = threadIdx.x;
    const int eb = blockIdx.x * 64;
    const int lane = t & 63, w = t >> 6, g = lane >> 4, l15 = lane & 15;

    if (t < 64) {
        int e = eb + t;
        int s = 0, d = -1;
        if (e < Etot) { s = esrc[e]; d = edst[e]; }
        srcl[t] = s; dstl[t] = d;
        int dd = (d < 0) ? 0 : d;
        float rx = posb[3 * s + 0] - posb[3 * dd + 0];
        float ry = posb[3 * s + 1] - posb[3 * dd + 1];
        float rz = posb[3 * s + 2] - posb[3 * dd + 2];
        float dist = sqrtf(rx * rx + ry * ry + rz * rz);
        relt[0][t] = rx; relt[1][t] = ry; relt[2][t] = rz;
        distl[t] = dist;
        wscl[t] = wnum[s] * __builtin_amdgcn_rcpf(dist + EPSV);
    }
    __syncthreads();

    // m1 = silu(U[dst] (b1 folded) + V[src] + dist*wt)
    #pragma unroll
    for (int j = 0; j < 4; ++j) {
        int f = t + 256 * j;              // 1024 = 64 rows x 16 octets
        int c8 = f & 15, row = f >> 4;
        bf16x8 res;
        if (dstl[row] >= 0) {
            int s = srcl[row], d = dstl[row];
            bf16x8 uv = *(const bf16x8*)(U16 + (size_t)d * 128 + c8 * 8);
            bf16x8 vv = *(const bf16x8*)(V16 + (size_t)s * 128 + c8 * 8);
            float wt[8];
            *(float4*)&wt[0] = *(const float4*)(W1tail + c8 * 8);
            *(float4*)&wt[4] = *(const float4*)(W1tail + c8 * 8 + 4);
            float dv = distl[row];
            #pragma unroll
            for (int k = 0; k < 8; ++k) {
                float x = bf2f(uv[k]) + bf2f(vv[k]) + dv * wt[k];
                res[k] = f2bfs(silu_f(x));
            }
        } else {
            #pragma unroll
            for (int k = 0; k < 8; ++k) res[k] = 0;
        }
        *(bf16x8*)(&m1s[row][c8 * 8]) = res;
    }
    __syncthreads();

    // GEMM2: m2 = m1 @ W2
    const int colA = w * 32 + l15, colB = colA + 16;
    f32x4 acc[4][2];
    zacc(acc);
    mfma_gemm<136>(m1s, 0, W2p, 4, w, lane, acc);
    __syncthreads();   // all m1s reads done; safe to overwrite with m2

    // write silu(m2 + b2) back into the same LDS (bf16)
    {
        float b2a = b2[colA], b2b = b2[colB];
        #pragma unroll
        for (int r = 0; r < 4; ++r)
            #pragma unroll
            for (int q = 0; q < 4; ++q) {
                int row = r * 16 + g * 4 + q;
                m1s[row][colA] = __float2bfloat16(silu_f(acc[r][0][q] + b2a));
                m1s[row][colB] = __float2bfloat16(silu_f(acc[r][1][q] + b2b));
            }
    }
    __syncthreads();

    // segmented reduction by dst (rows sorted): one atomic per (segment, col)
    {
        int col = t & 127, half = t >> 7;
        int r0 = half * 32;
        float a = 0.f;
        int cur = dstl[r0];
        #pragma unroll 4
        for (int r = r0; r < r0 + 32; ++r) {
            int d = dstl[r];
            if (d != cur) {
                if (cur >= 0) atomicAdd(&agg[(size_t)cur * 128 + col], a);
                a = 0.f; cur = d;
            }
            if (d >= 0) a += bf2f(*(const short*)&m1s[r][col]);
        }
        if (cur >= 0) atomicAdd(&agg[(size_t)cur * 128 + col], a);
    }

    // pdel scatter (per-edge, small)
    if (t < 192) {
        int e = t / 3, comp = t % 3;
        if (dstl[e] >= 0)
            atomicAdd(&pdel[(size_t)dstl[e] * 3 + comp], wscl[e] * relt[comp][e]);
    }
}

// ======================= per-layer node kernel (+ fused precompute for next layer)
__global__ __launch_bounds__(256) void node_mfma_kernel(
    float* __restrict__ hbuf, __hip_bfloat16* __restrict__ h16,
    const float* __restrict__ agg,
    float* __restrict__ posb, const float* __restrict__ pdel,
    const __hip_bfloat16* __restrict__ W1p, const float* __restrict__ b1,
    const __hip_bfloat16* __restrict__ W2p, const float* __restrict__ b2,
    const __hip_bfloat16* __restrict__ nxtW1p, const float* __restrict__ nxt_b1,
    const __hip_bfloat16* __restrict__ nxt_cW1p, const float* __restrict__ nxt_cb1,
    const float* __restrict__ nxt_cW2, const float* __restrict__ nxt_cb2,
    __hip_bfloat16* __restrict__ U16, __hip_bfloat16* __restrict__ V16,
    float* __restrict__ wnum,
    int N, int doPre)
{
    __shared__ __hip_bfloat16 a_t[64][264];   // [h | agg] then [newh | agg]
    __shared__ __hip_bfloat16 us[64][136];
    __shared__ float redw[64][4];
    const int t = threadIdx.x;
    const int nb = blockIdx.x * 64;
    const int lane = t & 63, w = t >> 6, g = lane >> 4, l15 = lane & 15;

    #pragma unroll
    for (int it = 0; it < 4; ++it) {
        int flat = t + 256 * it;
        int c = flat & 15, e = flat >> 4;
        int node = nb + e; if (node >= N) node = N - 1;
        *(int4*)(&a_t[e][c * 8]) = *(const int4*)(h16 + (size_t)node * 128 + c * 8);
    }
    #pragma unroll
    for (int it = 0; it < 8; ++it) {
        int flat = t + 256 * it;
        int c = flat & 31, e = flat >> 5;
        int node = nb + e; if (node >= N) node = N - 1;
        float4 v = *(const float4*)(agg + (size_t)node * 128 + c * 4);
        __hip_bfloat16* p = &a_t[e][128 + c * 4];
        p[0] = __float2bfloat16(v.x); p[1] = __float2bfloat16(v.y);
        p[2] = __float2bfloat16(v.z); p[3] = __float2bfloat16(v.w);
    }
    __syncthreads();

    const int colA = w * 32 + l15, colB = colA + 16;
    f32x4 acc[4][2];

    zacc(acc);
    mfma_gemm<264>(a_t, 0, W1p, 8, w, lane, acc);
    {
        float b1a = b1[colA], b1b = b1[colB];
        #pragma unroll
        for (int r = 0; r < 4; ++r)
            #pragma unroll
            for (int q = 0; q < 4; ++q) {
                int row = r * 16 + g * 4 + q;
                us[row][colA] = __float2bfloat16(silu_f(acc[r][0][q] + b1a));
                us[row][colB] = __float2bfloat16(silu_f(acc[r][1][q] + b1b));
            }
    }
    __syncthreads();

    zacc(acc);
    mfma_gemm<136>(us, 0, W2p, 4, w, lane, acc);
    {
        float b2a = b2[colA], b2b = b2[colB];
        #pragma unroll
        for (int r = 0; r < 4; ++r)
            #pragma unroll
            for (int q = 0; q < 4; ++q) {
                int row = r * 16 + g * 4 + q;
                int node = nb + row;
                if (node < N) {
                    size_t off = (size_t)node * 128;
                    float va = hbuf[off + colA] + acc[r][0][q] + b2a;
                    float vb = hbuf[off + colB] + acc[r][1][q] + b2b;
                    hbuf[off + colA] = va; hbuf[off + colB] = vb;
                    __hip_bfloat16 ha = __float2bfloat16(va), hb = __float2bfloat16(vb);
                    h16[off + colA] = ha; h16[off + colB] = hb;
                    a_t[row][colA] = ha; a_t[row][colB] = hb;
                } else {
                    a_t[row][colA] = __float2bfloat16(0.f);
                    a_t[row][colB] = __float2bfloat16(0.f);
                }
            }
    }
    if (t < 192) {
        int e = t / 3, comp = t % 3;
        int node = nb + e;
        if (node < N) posb[3 * node + comp] += pdel[3 * node + comp];
    }

    if (!doPre) return;
    __syncthreads();

    // U_next = newh @ W1a_next + b1_next
    zacc(acc);
    mfma_gemm<264>(a_t, 0, nxtW1p, 4, w, lane, acc);
    {
        float bA = nxt_b1[colA], bB = nxt_b1[colB];
        #pragma unroll
        for (int r = 0; r < 4; ++r)
            #pragma unroll
            for (int q = 0; q < 4; ++q) {
                int node = nb + r * 16 + g * 4 + q;
                if (node < N) {
                    U16[(size_t)node * 128 + colA] = __float2bfloat16(acc[r][0][q] + bA);
                    U16[(size_t)node * 128 + colB] = __float2bfloat16(acc[r][1][q] + bB);
                }
            }
    }
    // V_next = newh @ W1b_next
    zacc(acc);
    mfma_gemm<264>(a_t, 0, nxtW1p + 4 * 4096, 4, w, lane, acc);
    #pragma unroll
    for (int r = 0; r < 4; ++r)
        #pragma unroll
        for (int q = 0; q < 4; ++q) {
            int node = nb + r * 16 + g * 4 + q;
            if (node < N) {
                V16[(size_t)node * 128 + colA] = __float2bfloat16(acc[r][0][q]);
                V16[(size_t)node * 128 + colB] = __float2bfloat16(acc[r][1][q]);
            }
        }
    // wnum_next
    zacc(acc);
    mfma_gemm<264>(a_t, 0, nxt_cW1p, 4, w, lane, acc);
    {
        float cb1A = nxt_cb1[colA], cb1B = nxt_cb1[colB];
        float wA = nxt_cW2[colA], wB = nxt_cW2[colB];
        #pragma unroll
        for (int r = 0; r < 4; ++r)
            #pragma unroll
            for (int q = 0; q < 4; ++q) {
                float p = silu_f(acc[r][0][q] + cb1A) * wA
                        + silu_f(acc[r][1][q] + cb1B) * wB;
                p += __shfl_xor(p, 1);
                p += __shfl_xor(p, 2);
                p += __shfl_xor(p, 4);
                p += __shfl_xor(p, 8);
                if (l15 == 0) redw[r * 16 + g * 4 + q][w] = p;
            }
    }
    __syncthreads();
    if (t < 64 && nb + t < N)
        wnum[nb + t] = redw[t][0] + redw[t][1] + redw[t][2] + redw[t][3] + nxt_cb2[0];
}

// ======================= output head (MFMA)
__global__ __launch_bounds__(256) void out_mfma_kernel(
    const __hip_bfloat16* __restrict__ h16,
    const __hip_bfloat16* __restrict__ W1p, const float* __restrict__ b1,
    const __hip_bfloat16* __restrict__ W2p, const float* __restrict__ b2,
    float* __restrict__ outp, int N)
{
    __shared__ __hip_bfloat16 a8[64][136];
    __shared__ __hip_bfloat16 us[64][136];
    const int t = threadIdx.x;
    const int nb = blockIdx.x * 64;
    const int lane = t & 63, w = t >> 6, g = lane >> 4;

    #pragma unroll
    for (int it = 0; it < 4; ++it) {
        int flat = t + 256 * it;
        int c = flat & 15, e = flat >> 4;
        int node = nb + e; if (node >= N) node = N - 1;
        *(int4*)(&a8[e][c * 8]) = *(const int4*)(h16 + (size_t)node * 128 + c * 8);
    }
    __syncthreads();

    const int colA = w * 32 + (lane & 15), colB = colA + 16;
    f32x4 acc[4][2];

    zacc(acc);
    mfma_gemm<136>(a8, 0, W1p, 4, w, lane, acc);
    {
        float b1a = b1[colA], b1b = b1[colB];
        #pragma unroll
        for (int r = 0; r < 4; ++r)
            #pragma unroll
            for (int q = 0; q < 4; ++q) {
                int row = r * 16 + g * 4 + q;
                us[row][colA] = __float2bfloat16(silu_f(acc[r][0][q] + b1a));
                us[row][colB] = __float2bfloat16(silu_f(acc[r][1][q] + b1b));
            }
    }
    __syncthreads();

    zacc(acc);
    mfma_gemm<136>(us, 0, W2p, 4, w, lane, acc);
    {
        float b2a = b2[colA], b2b = b2[colB];
        #pragma unroll
        for (int r = 0; r < 4; ++r)
            #pragma unroll
            for (int q = 0; q < 4; ++q) {
                int row = r * 16 + g * 4 + q;
                int node = nb + row;
                if (node < N) {
                    outp[(size_t)node * 128 + colA] = acc[r][0][q] + b2a;
                    outp[(size_t)node * 128 + colB] = acc[r][1][q] + b2b;
                }
            }
    }
}

// =======================
extern "C" void kernel_launch(void* const* d_in, const int* in_sizes, int n_in,
                              void* d_out, int out_size, void* d_ws, size_t ws_size,
                              hipStream_t stream)
{
    const float* hin  = (const float*)d_in[0];
    const float* pos  = (const float*)d_in[1];
    const int*   ei   = (const int*)d_in[2];
    const float* embW = (const float*)d_in[3];
    const float* embb = (const float*)d_in[4];
    const float* mW1  = (const float*)d_in[5];
    const float* mb1  = (const float*)d_in[6];
    const float* mW2  = (const float*)d_in[7];
    const float* mb2  = (const float*)d_in[8];
    const float* cW1  = (const float*)d_in[9];
    const float* cb1  = (const float*)d_in[10];
    const float* cW2  = (const float*)d_in[11];
    const float* cb2  = (const float*)d_in[12];
    const float* nW1  = (const float*)d_in[13];
    const float* nb1  = (const float*)d_in[14];
    const float* nW2  = (const float*)d_in[15];
    const float* nb2  = (const float*)d_in[16];
    const float* oW1  = (const float*)d_in[17];
    const float* ob1  = (const float*)d_in[18];
    const float* oW2  = (const float*)d_in[19];
    const float* ob2  = (const float*)d_in[20];

    const int N = in_sizes[0] / 64;
    const int E = in_sizes[2] / 2;
    const int Etot = E + N;

    float* hbuf = (float*)d_ws;                                  // N*128 f32
    float* aggb = hbuf + (size_t)N * 128;                        // N*128 f32
    float* posb = aggb + (size_t)N * 128;                        // N*3
    float* pdel = posb + (size_t)N * 3;                          // N*3
    float* wnum = pdel + (size_t)N * 3;                          // N f32
    __hip_bfloat16* h16 = (__hip_bfloat16*)(wnum + N);           // N*128 bf16
    __hip_bfloat16* U16 = h16 + (size_t)N * 128;                 // N*128 bf16
    __hip_bfloat16* V16 = U16 + (size_t)N * 128;                 // N*128 bf16
    __hip_bfloat16* packed = V16 + (size_t)N * 128;              // 120*4096 bf16
    int* cnt  = (int*)(packed + 120 * 4096);                     // N
    int* soff = cnt + N;                                         // N
    int* part = soff + N;                                        // 64
    int* esrc = part + 64;                                       // Etot
    int* edst = esrc + Etot;                                     // Etot
    float* outp = (float*)d_out;

    PackArgs pa;
    int nm = 0; unsigned int poff = 0; int totalChunks = 0;
    auto addm = [&](const float* s, int kc) {
        pa.src[nm] = s; pa.doff[nm] = poff; pa.nchunk[nm] = kc;
        poff += (unsigned int)kc * 4096; totalChunks += kc; ++nm;
    };
    for (int l = 0; l < 4; ++l) {
        addm(mW1 + (size_t)l * 257 * 128, 8);
        addm(mW2 + (size_t)l * 128 * 128, 4);
        addm(cW1 + (size_t)l * 128 * 128, 4);
        addm(nW1 + (size_t)l * 256 * 128, 8);
        addm(nW2 + (size_t)l * 128 * 128, 4);
    }
    addm(oW1, 4);
    addm(oW2, 4);
    pa.nmat = nm;

    const unsigned int LSTRIDE = 28 * 4096;

    hipMemcpyAsync(posb, pos, (size_t)N * 3 * sizeof(float),
                   hipMemcpyDeviceToDevice, stream);
    repack_kernel<<<totalChunks, 256, 0, stream>>>(pa, packed);

    const int scanBlocks = (N + 4095) / 4096;
    hipMemsetAsync(cnt, 0, (size_t)N * sizeof(int), stream);
    hist_kernel<<<(Etot + 255) / 256, 256, 0, stream>>>(ei, cnt, E, N);
    scan_block_kernel<<<scanBlocks, 256, 0, stream>>>(cnt, soff, part, N);
    scan_part_kernel<<<1, 64, 0, stream>>>(part, scanBlocks);
    scan_add_kernel<<<scanBlocks, 256, 0, stream>>>(soff, part, N);
    scatter_kernel<<<(Etot + 255) / 256, 256, 0, stream>>>(ei, soff, esrc, edst, E, N);

    const int nodeBlocks32 = (N + 31) / 32;
    const int nodeBlocks64 = (N + 63) / 64;
    const int edgeBlocks   = (Etot + 63) / 64;

    embed_kernel<<<nodeBlocks32, 256, 0, stream>>>(hin, embW, embb, hbuf, h16, N);

    precompute_kernel<<<nodeBlocks64, 256, 0, stream>>>(
        h16, packed, mb1, packed + 12 * 4096,
        cb1, cW2, cb2, U16, V16, wnum, N);

    for (int l = 0; l < 4; ++l) {
        hipMemsetAsync(aggb, 0, (size_t)N * 128 * sizeof(float), stream);
        hipMemsetAsync(pdel, 0, (size_t)N * 3 * sizeof(float), stream);
        const __hip_bfloat16* lp = packed + (size_t)l * LSTRIDE;
        edge_kernel<<<edgeBlocks, 256, 0, stream>>>(
            U16, V16, wnum, posb, esrc, edst,
            mW1 + (size_t)l * 257 * 128 + 256 * 128,
            lp + 8 * 4096, mb2 + l * 128,
            aggb, pdel, Etot);
        const int ln = (l < 3) ? (l + 1) : l;
        const __hip_bfloat16* lpn = packed + (size_t)ln * LSTRIDE;
        node_mfma_kernel<<<nodeBlocks64, 256, 0, stream>>>(
            hbuf, h16, aggb, posb, pdel,
            lp + 16 * 4096, nb1 + l * 128,
            lp + 24 * 4096, nb2 + l * 128,
            lpn, mb1 + (size_t)ln * 128,
            lpn + 12 * 4096, cb1 + (size_t)ln * 128,
            cW2 + (size_t)ln * 128, cb2 + ln,
            U16, V16, wnum,
            N, (l < 3) ? 1 : 0);
    }
    out_mfma_kernel<<<nodeBlocks64, 256, 0, stream>>>(
        h16, packed + (size_t)4 * LSTRIDE, ob1,
        packed + (size_t)4 * LSTRIDE + 4 * 4096, ob2, outp, N);

    hipMemcpyAsync(outp + (size_t)N * 128, posb, (size_t)N * 3 * sizeof(float),
                   hipMemcpyDeviceToDevice, stream);
}